// Round 2
// baseline (520.938 us; speedup 1.0000x reference)
//
#include <hip/hip_runtime.h>
#include <math.h>

// ---------------------------------------------------------------------------
// gram = x^T x (N=4M, D=10, fp64-accurate accumulation) -> round to fp32 ->
// LAPACK-faithful fp32 ssyevd path (ssytd2 'L' + ssteqr w/ LAPACK>=3.10
// slartg) on the 10x10, single thread -> tiny MLP -> 0.5*(sigmoid+1).
// fp32 is essential: ssteqr's deflation/split branches scale with eps, and
// the harness references (jax x32 + numpy on fp32) both run fp32 ssyevd.
// ---------------------------------------------------------------------------

#define BLK2 256
#define GRID2 1024

__global__ void zero_ws_kernel(double* __restrict__ g) {
  int t = threadIdx.x;
  if (t < 55) g[t] = 0.0;
}

__global__ __launch_bounds__(BLK2) void gram_kernel(const float* __restrict__ x,
                                                    double* __restrict__ g,
                                                    int npairs) {
  float acc[55];
#pragma unroll
  for (int k = 0; k < 55; k++) acc[k] = 0.0f;

  int tid = blockIdx.x * BLK2 + threadIdx.x;
  const int stride = GRID2 * BLK2;

  for (int p = tid; p < npairs; p += stride) {
    const float4* base = (const float4*)(x + (size_t)p * 20);  // 80B, 16B-aligned
    float4 q0 = base[0], q1 = base[1], q2 = base[2], q3 = base[3], q4 = base[4];
    float v[20] = {q0.x, q0.y, q0.z, q0.w, q1.x, q1.y, q1.z, q1.w,
                   q2.x, q2.y, q2.z, q2.w, q3.x, q3.y, q3.z, q3.w,
                   q4.x, q4.y, q4.z, q4.w};
    int k = 0;
#pragma unroll
    for (int i = 0; i < 10; i++) {
#pragma unroll
      for (int j = 0; j <= i; j++) {
        acc[k] += v[i] * v[j] + v[10 + i] * v[10 + j];
        k++;
      }
    }
  }

  __shared__ double sred[4][55];
  int lane = threadIdx.x & 63;
  int wv = threadIdx.x >> 6;
#pragma unroll
  for (int k = 0; k < 55; k++) {
    double d = (double)acc[k];
#pragma unroll
    for (int off = 32; off > 0; off >>= 1) d += __shfl_down(d, off, 64);
    if (lane == 0) sred[wv][k] = d;
  }
  __syncthreads();
  if (threadIdx.x < 55) {
    double s = sred[0][threadIdx.x] + sred[1][threadIdx.x] +
               sred[2][threadIdx.x] + sred[3][threadIdx.x];
    atomicAdd(&g[threadIdx.x], s);
  }
}

// ------------------------- LAPACK helpers (fp32) ---------------------------

__device__ inline float sf_sign(float a, float b) {
  return (b >= 0.0f) ? fabsf(a) : -fabsf(a);
}

__device__ inline float slapy2(float x, float y) {
  float xa = fabsf(x), ya = fabsf(y);
  float w = fmaxf(xa, ya), z = fminf(xa, ya);
  if (z == 0.0f) return w;
  float q = z / w;
  return w * sqrtf(1.0f + q * q);
}

// LAPACK >= 3.10 slartg: c = |f|/d >= 0, r = sign(f)*d, s = g/r
__device__ inline void slartg(float f, float g, float* c, float* s, float* r) {
  if (g == 0.0f) {
    *c = 1.0f; *s = 0.0f; *r = f;
  } else if (f == 0.0f) {
    *c = 0.0f; *s = sf_sign(1.0f, g); *r = fabsf(g);
  } else {
    float d = sqrtf(f * f + g * g);
    *c = fabsf(f) / d;
    float rr = sf_sign(d, f);
    *s = g / rr;
    *r = rr;
  }
}

__device__ inline void slaev2(float a, float b, float c,
                              float* rt1, float* rt2, float* cs1, float* sn1) {
  float sm = a + c;
  float df = a - c;
  float adf = fabsf(df);
  float tb = b + b;
  float ab = fabsf(tb);
  float acmx, acmn;
  if (fabsf(a) > fabsf(c)) { acmx = a; acmn = c; } else { acmx = c; acmn = a; }
  float rt;
  if (adf > ab)      { float t = ab / adf; rt = adf * sqrtf(1.0f + t * t); }
  else if (adf < ab) { float t = adf / ab; rt = ab * sqrtf(1.0f + t * t); }
  else               { rt = ab * sqrtf(2.0f); }
  int sgn1;
  if (sm < 0.0f) {
    *rt1 = 0.5f * (sm - rt); sgn1 = -1;
    *rt2 = (acmx / *rt1) * acmn - (b / *rt1) * b;
  } else if (sm > 0.0f) {
    *rt1 = 0.5f * (sm + rt); sgn1 = 1;
    *rt2 = (acmx / *rt1) * acmn - (b / *rt1) * b;
  } else {
    *rt1 = 0.5f * rt; *rt2 = -0.5f * rt; sgn1 = 1;
  }
  int sgn2;
  float cs;
  if (df >= 0.0f) { cs = df + rt; sgn2 = 1; } else { cs = df - rt; sgn2 = -1; }
  float acs = fabsf(cs);
  if (acs > ab) {
    float ct = -tb / cs;
    *sn1 = 1.0f / sqrtf(1.0f + ct * ct);
    *cs1 = ct * (*sn1);
  } else {
    if (ab == 0.0f) { *cs1 = 1.0f; *sn1 = 0.0f; }
    else {
      float tn = -cs / tb;
      *cs1 = 1.0f / sqrtf(1.0f + tn * tn);
      *sn1 = tn * (*cs1);
    }
  }
  if (sgn1 == sgn2) { float tn = *cs1; *cs1 = -(*sn1); *sn1 = tn; }
}

// 1-based access macros mirroring the Fortran
#define A_(r, c) Am[(r)-1][(c)-1]
#define Z_(r, c) Zm[(r)-1][(c)-1]
#define D_(i) dv[(i)-1]
#define E_(i) ev[(i)-1]
#define TAUV(i) tauv[(i)-1]
#define WV(i) wvv[(i)-1]
#define CS_(i) csv[(i)-1]
#define SN_(i) snv[(i)-1]

__global__ void eig_mlp_kernel(const double* __restrict__ g,
                               const float* __restrict__ W1,
                               const float* __restrict__ b1,
                               const float* __restrict__ W2,
                               const float* __restrict__ b2,
                               float* __restrict__ out) {
  if (threadIdx.x != 0 || blockIdx.x != 0) return;
  const int n = 10;
  float Am[10][10], Zm[10][10];
  float dv[10], ev[10], tauv[10], wvv[10], csv[10], snv[10];

  // load gram (lower-packed, k = i*(i+1)/2 + j), round to fp32
  {
    int k = 0;
    for (int i = 0; i < 10; i++)
      for (int j = 0; j <= i; j++) {
        float v = (float)g[k++];
        Am[i][j] = v;
        Am[j][i] = v;
      }
  }

  // -------- ssytd2 (UPLO='L') --------
  for (int i = 1; i <= n - 1; i++) {
    int nmi = n - i;
    float alpha = A_(i + 1, i);
    float taui = 0.0f;
    if (nmi > 1) {
      float ss = 0.0f;
      for (int r = i + 2; r <= n; r++) { float t = A_(r, i); ss += t * t; }
      float xnorm = sqrtf(ss);
      if (xnorm != 0.0f) {
        float beta = -sf_sign(slapy2(alpha, xnorm), alpha);
        taui = (beta - alpha) / beta;
        float sc = 1.0f / (alpha - beta);
        for (int r = i + 2; r <= n; r++) A_(r, i) *= sc;
        alpha = beta;
      }
    }
    E_(i) = alpha;
    A_(i + 1, i) = alpha;
    if (taui != 0.0f) {
      A_(i + 1, i) = 1.0f;
      // w = taui * A(sub, symmetric from lower) * v
      for (int r = i + 1; r <= n; r++) {
        float s = 0.0f;
        for (int c = i + 1; c <= n; c++) {
          float arc = (r >= c) ? A_(r, c) : A_(c, r);
          s += arc * A_(c, i);
        }
        WV(r) = taui * s;
      }
      float dot = 0.0f;
      for (int r = i + 1; r <= n; r++) dot += WV(r) * A_(r, i);
      float al2 = -0.5f * taui * dot;
      for (int r = i + 1; r <= n; r++) WV(r) += al2 * A_(r, i);
      // rank-2 update, lower only
      for (int c = i + 1; c <= n; c++)
        for (int r = c; r <= n; r++)
          A_(r, c) -= A_(r, i) * WV(c) + WV(r) * A_(c, i);
      A_(i + 1, i) = E_(i);
    }
    D_(i) = A_(i, i);
    TAUV(i) = taui;
  }
  D_(n) = A_(n, n);

  // -------- form Q0 = H(1)...H(n-1): Z = I; Z = H(i) Z for i = n-1..1 -----
  for (int r = 1; r <= n; r++)
    for (int c = 1; c <= n; c++) Z_(r, c) = (r == c) ? 1.0f : 0.0f;
  for (int i = n - 1; i >= 1; i--) {
    float taui = TAUV(i);
    if (taui == 0.0f) continue;
    for (int c = 1; c <= n; c++) {
      float t = Z_(i + 1, c);
      for (int r = i + 2; r <= n; r++) t += A_(r, i) * Z_(r, c);
      t *= taui;
      Z_(i + 1, c) -= t;
      for (int r = i + 2; r <= n; r++) Z_(r, c) -= A_(r, i) * t;
    }
  }

  // -------- ssteqr ('V'); fp32 constants are branch-critical -------------
  const float eps = 5.9604644775390625e-08f;   // 2^-24 = SLAMCH('E')
  const float eps2 = eps * eps;
  const float safmin = 1.17549435082228751e-38f;  // 2^-126
  int nmaxit = n * 30, jtot = 0;
  int l1 = 1;
  int guard = 0;

  while (l1 <= n && guard++ < 2000) {
    int m;
    if (l1 > 1) E_(l1 - 1) = 0.0f;
    for (m = l1; m <= n - 1; m++) {
      float tst = fabsf(E_(m));
      if (tst == 0.0f) break;
      if (tst <= (sqrtf(fabsf(D_(m))) * sqrtf(fabsf(D_(m + 1)))) * eps) {
        E_(m) = 0.0f;
        break;
      }
    }
    int l = l1, lsv = l, lend = m, lendsv = m;
    l1 = m + 1;
    if (lend == l) continue;
    if (fabsf(D_(lend)) < fabsf(D_(l))) { lend = lsv; l = lendsv; }

    if (lend > l) {
      // ---------------- QL iteration ----------------
      for (;;) {
        if (guard++ > 4000) break;
        if (l != lend) {
          for (m = l; m <= lend - 1; m++) {
            float tst = E_(m) * E_(m);
            if (tst <= (eps2 * fabsf(D_(m))) * fabsf(D_(m + 1)) + safmin) break;
          }
        } else m = lend;
        if (m < lend) E_(m) = 0.0f;
        float p = D_(l);
        if (m == l) {               // eigenvalue found
          D_(l) = p;
          l = l + 1;
          if (l <= lend) continue;
          break;
        }
        if (m == l + 1) {           // 2x2 block
          float rt1, rt2, c2, s2;
          slaev2(D_(l), E_(l), D_(l + 1), &rt1, &rt2, &c2, &s2);
          for (int r = 1; r <= n; r++) {
            float t = Z_(r, l + 1);
            Z_(r, l + 1) = c2 * t - s2 * Z_(r, l);
            Z_(r, l)     = s2 * t + c2 * Z_(r, l);
          }
          D_(l) = rt1; D_(l + 1) = rt2; E_(l) = 0.0f;
          l = l + 2;
          if (l <= lend) continue;
          break;
        }
        if (jtot == nmaxit) break;
        jtot++;
        float gg = (D_(l + 1) - p) / (2.0f * E_(l));
        float rr = slapy2(gg, 1.0f);
        gg = D_(m) - p + (E_(l) / (gg + sf_sign(rr, gg)));
        float s = 1.0f, c = 1.0f;
        p = 0.0f;
        for (int i = m - 1; i >= l; i--) {
          float f = s * E_(i);
          float b = c * E_(i);
          slartg(gg, f, &c, &s, &rr);
          if (i != m - 1) E_(i + 1) = rr;
          gg = D_(i + 1) - p;
          rr = (D_(i) - gg) * s + 2.0f * c * b;
          p = s * rr;
          D_(i + 1) = gg + p;
          gg = c * rr - b;
          CS_(i) = c;
          SN_(i) = -s;
        }
        // slasr 'R','V','B' on columns l..m
        for (int j = m - 1; j >= l; j--) {
          float cj = CS_(j), sj = SN_(j);
          for (int r = 1; r <= n; r++) {
            float t = Z_(r, j + 1);
            Z_(r, j + 1) = cj * t - sj * Z_(r, j);
            Z_(r, j)     = sj * t + cj * Z_(r, j);
          }
        }
        D_(l) = D_(l) - p;
        E_(l) = gg;
      }
    } else {
      // ---------------- QR iteration ----------------
      for (;;) {
        if (guard++ > 4000) break;
        if (l != lend) {
          for (m = l; m >= lend + 1; m--) {
            float tst = E_(m - 1) * E_(m - 1);
            if (tst <= (eps2 * fabsf(D_(m))) * fabsf(D_(m - 1)) + safmin) break;
          }
        } else m = lend;
        if (m > lend) E_(m - 1) = 0.0f;
        float p = D_(l);
        if (m == l) {               // eigenvalue found
          D_(l) = p;
          l = l - 1;
          if (l >= lend) continue;
          break;
        }
        if (m == l - 1) {           // 2x2 block
          float rt1, rt2, c2, s2;
          slaev2(D_(l - 1), E_(l - 1), D_(l), &rt1, &rt2, &c2, &s2);
          for (int r = 1; r <= n; r++) {
            float t = Z_(r, l);
            Z_(r, l)     = c2 * t - s2 * Z_(r, l - 1);
            Z_(r, l - 1) = s2 * t + c2 * Z_(r, l - 1);
          }
          D_(l - 1) = rt1; D_(l) = rt2; E_(l - 1) = 0.0f;
          l = l - 2;
          if (l >= lend) continue;
          break;
        }
        if (jtot == nmaxit) break;
        jtot++;
        float gg = (D_(l - 1) - p) / (2.0f * E_(l - 1));
        float rr = slapy2(gg, 1.0f);
        gg = D_(m) - p + (E_(l - 1) / (gg + sf_sign(rr, gg)));
        float s = 1.0f, c = 1.0f;
        p = 0.0f;
        for (int i = m; i <= l - 1; i++) {
          float f = s * E_(i);
          float b = c * E_(i);
          slartg(gg, f, &c, &s, &rr);
          if (i != m) E_(i - 1) = rr;
          gg = D_(i) - p;
          rr = (D_(i + 1) - gg) * s + 2.0f * c * b;
          p = s * rr;
          D_(i) = gg + p;
          gg = c * rr - b;
          CS_(i) = c;
          SN_(i) = s;
        }
        // slasr 'R','V','F' on columns m..l
        for (int j = m; j <= l - 1; j++) {
          float cj = CS_(j), sj = SN_(j);
          for (int r = 1; r <= n; r++) {
            float t = Z_(r, j + 1);
            Z_(r, j + 1) = cj * t - sj * Z_(r, j);
            Z_(r, j)     = sj * t + cj * Z_(r, j);
          }
        }
        D_(l) = D_(l) - p;
        E_(l - 1) = gg;
      }
    }
  }

  // -------- selection sort ascending (as in ssteqr) --------
  for (int ii = 2; ii <= n; ii++) {
    int i = ii - 1, k = i;
    float p = D_(i);
    for (int j = ii; j <= n; j++)
      if (D_(j) < p) { k = j; p = D_(j); }
    if (k != i) {
      D_(k) = D_(i);
      D_(i) = p;
      for (int r = 1; r <= n; r++) {
        float t = Z_(r, i);
        Z_(r, i) = Z_(r, k);
        Z_(r, k) = t;
      }
    }
  }

  // -------- MLP: relu(w @ W1^T + b1) @ W2^T + b2 -> 0.5*(sigmoid+1) ------
  for (int r = 0; r < 10; r++) {
    double o = (double)b2[0];
    for (int h = 0; h < 16; h++) {
      double sgm = (double)b1[h];
      for (int k = 0; k < 10; k++) sgm += (double)Zm[r][k] * (double)W1[h * 10 + k];
      if (sgm > 0.0) o += sgm * (double)W2[h];
    }
    double sig = 1.0 / (1.0 + exp(-o));
    out[r] = (float)(0.5 * (sig + 1.0));
  }
}

extern "C" void kernel_launch(void* const* d_in, const int* in_sizes, int n_in,
                              void* d_out, int out_size, void* d_ws, size_t ws_size,
                              hipStream_t stream) {
  const float* x  = (const float*)d_in[0];
  const float* W1 = (const float*)d_in[1];
  const float* b1 = (const float*)d_in[2];
  const float* W2 = (const float*)d_in[3];
  const float* b2 = (const float*)d_in[4];
  double* g = (double*)d_ws;
  float* out = (float*)d_out;

  int nrows = in_sizes[0] / 10;
  int npairs = nrows / 2;

  zero_ws_kernel<<<1, 64, 0, stream>>>(g);
  gram_kernel<<<GRID2, BLK2, 0, stream>>>(x, g, npairs);
  eig_mlp_kernel<<<1, 64, 0, stream>>>(g, W1, b1, W2, b2, out);
}

// Round 3
// 378.029 us; speedup vs baseline: 1.3780x; 1.3780x over previous
//
#include <hip/hip_runtime.h>
#include <math.h>

// ---------------------------------------------------------------------------
// gram = x^T x (N=4M, D=10, fp64 accumulation) -> fp32 -> LAPACK-faithful
// fp32 ssyevd path (ssytd2 'L' + ssteqr, LAPACK>=3.10 slartg) -> MLP.
// Round 3: eig kernel made fully register-resident. All arrays are accessed
// with compile-time indices (full unroll + range masks + 10-way select for
// runtime l/m indices) so SROA promotes them to VGPRs — round 2's 274 us was
// scratch-memory latency (FETCH_SIZE 51KB on a 600B-input kernel).
// Arithmetic op sequence is identical to the passing round-2 kernel.
// ---------------------------------------------------------------------------

#define BLK2 256
#define GRID2 1024

__global__ void zero_ws_kernel(double* __restrict__ g) {
  int t = threadIdx.x;
  if (t < 55) g[t] = 0.0;
}

__global__ __launch_bounds__(BLK2) void gram_kernel(const float* __restrict__ x,
                                                    double* __restrict__ g,
                                                    int npairs) {
  float acc[55];
#pragma unroll
  for (int k = 0; k < 55; k++) acc[k] = 0.0f;

  int tid = blockIdx.x * BLK2 + threadIdx.x;
  const int stride = GRID2 * BLK2;

  for (int p = tid; p < npairs; p += stride) {
    const float4* base = (const float4*)(x + (size_t)p * 20);  // 80B, 16B-aligned
    float4 q0 = base[0], q1 = base[1], q2 = base[2], q3 = base[3], q4 = base[4];
    float v[20] = {q0.x, q0.y, q0.z, q0.w, q1.x, q1.y, q1.z, q1.w,
                   q2.x, q2.y, q2.z, q2.w, q3.x, q3.y, q3.z, q3.w,
                   q4.x, q4.y, q4.z, q4.w};
    int k = 0;
#pragma unroll
    for (int i = 0; i < 10; i++) {
#pragma unroll
      for (int j = 0; j <= i; j++) {
        acc[k] += v[i] * v[j] + v[10 + i] * v[10 + j];
        k++;
      }
    }
  }

  __shared__ double sred[4][55];
  int lane = threadIdx.x & 63;
  int wv = threadIdx.x >> 6;
#pragma unroll
  for (int k = 0; k < 55; k++) {
    double d = (double)acc[k];
#pragma unroll
    for (int off = 32; off > 0; off >>= 1) d += __shfl_down(d, off, 64);
    if (lane == 0) sred[wv][k] = d;
  }
  __syncthreads();
  if (threadIdx.x < 55) {
    double s = sred[0][threadIdx.x] + sred[1][threadIdx.x] +
               sred[2][threadIdx.x] + sred[3][threadIdx.x];
    atomicAdd(&g[threadIdx.x], s);
  }
}

// ------------------------- LAPACK helpers (fp32) ---------------------------

__device__ __forceinline__ float sf_sign(float a, float b) {
  return (b >= 0.0f) ? fabsf(a) : -fabsf(a);
}

__device__ __forceinline__ float slapy2(float x, float y) {
  float xa = fabsf(x), ya = fabsf(y);
  float w = fmaxf(xa, ya), z = fminf(xa, ya);
  if (z == 0.0f) return w;
  float q = z / w;
  return w * sqrtf(1.0f + q * q);
}

// LAPACK >= 3.10 slartg: c = |f|/d >= 0, r = sign(f)*d, s = g/r
__device__ __forceinline__ void slartg(float f, float g, float* c, float* s, float* r) {
  if (g == 0.0f) {
    *c = 1.0f; *s = 0.0f; *r = f;
  } else if (f == 0.0f) {
    *c = 0.0f; *s = sf_sign(1.0f, g); *r = fabsf(g);
  } else {
    float d = sqrtf(f * f + g * g);
    *c = fabsf(f) / d;
    float rr = sf_sign(d, f);
    *s = g / rr;
    *r = rr;
  }
}

__device__ __forceinline__ void slaev2(float a, float b, float c,
                                       float* rt1, float* rt2, float* cs1, float* sn1) {
  float sm = a + c;
  float df = a - c;
  float adf = fabsf(df);
  float tb = b + b;
  float ab = fabsf(tb);
  float acmx, acmn;
  if (fabsf(a) > fabsf(c)) { acmx = a; acmn = c; } else { acmx = c; acmn = a; }
  float rt;
  if (adf > ab)      { float t = ab / adf; rt = adf * sqrtf(1.0f + t * t); }
  else if (adf < ab) { float t = adf / ab; rt = ab * sqrtf(1.0f + t * t); }
  else               { rt = ab * sqrtf(2.0f); }
  int sgn1;
  if (sm < 0.0f) {
    *rt1 = 0.5f * (sm - rt); sgn1 = -1;
    *rt2 = (acmx / *rt1) * acmn - (b / *rt1) * b;
  } else if (sm > 0.0f) {
    *rt1 = 0.5f * (sm + rt); sgn1 = 1;
    *rt2 = (acmx / *rt1) * acmn - (b / *rt1) * b;
  } else {
    *rt1 = 0.5f * rt; *rt2 = -0.5f * rt; sgn1 = 1;
  }
  int sgn2;
  float cs;
  if (df >= 0.0f) { cs = df + rt; sgn2 = 1; } else { cs = df - rt; sgn2 = -1; }
  float acs = fabsf(cs);
  if (acs > ab) {
    float ct = -tb / cs;
    *sn1 = 1.0f / sqrtf(1.0f + ct * ct);
    *cs1 = ct * (*sn1);
  } else {
    if (ab == 0.0f) { *cs1 = 1.0f; *sn1 = 0.0f; }
    else {
      float tn = -cs / tb;
      *cs1 = 1.0f / sqrtf(1.0f + tn * tn);
      *sn1 = tn * (*cs1);
    }
  }
  if (sgn1 == sgn2) { float tn = *cs1; *cs1 = -(*sn1); *sn1 = tn; }
}

// 10-way register select / masked write (runtime idx0 is 0-based)
__device__ __forceinline__ float sel10(const float* a, int idx0) {
  float v = 0.0f;
#pragma unroll
  for (int k = 0; k < 10; k++) if (k == idx0) v = a[k];
  return v;
}
__device__ __forceinline__ void put10(float* a, int idx0, float v) {
#pragma unroll
  for (int k = 0; k < 10; k++) if (k == idx0) a[k] = v;
}

// static 1-based access macros (r,c,i must be compile-time constants)
#define A_(r, c) Am[((r)-1) * 10 + ((c)-1)]
#define Z_(r, c) Zm[((r)-1) * 10 + ((c)-1)]
#define D_(i) dv[(i)-1]
#define E_(i) ev[(i)-1]
#define TAUV(i) tauv[(i)-1]
#define WV(i) wvv[(i)-1]
#define CS_(i) csv[(i)-1]
#define SN_(i) snv[(i)-1]

__global__ __launch_bounds__(64, 1) void eig_mlp_kernel(
    const double* __restrict__ g,
    const float* __restrict__ W1,
    const float* __restrict__ b1,
    const float* __restrict__ W2,
    const float* __restrict__ b2,
    float* __restrict__ out) {
  if (threadIdx.x != 0 || blockIdx.x != 0) return;
  const int n = 10;
  float Am[100], Zm[100];
  float dv[10], ev[10], tauv[10], wvv[10], csv[10], snv[10];

  // load gram (lower-packed, k = i*(i+1)/2 + j), round to fp32
  {
    int k = 0;
#pragma unroll
    for (int i = 0; i < 10; i++)
#pragma unroll
      for (int j = 0; j <= i; j++) {
        float v = (float)g[k++];
        Am[i * 10 + j] = v;
        Am[j * 10 + i] = v;
      }
  }

  // -------- ssytd2 (UPLO='L'), i static --------
#pragma unroll
  for (int i = 1; i <= n - 1; i++) {
    const int nmi = n - i;
    float alpha = A_(i + 1, i);
    float taui = 0.0f;
    if (nmi > 1) {
      float ss = 0.0f;
#pragma unroll
      for (int r = i + 2; r <= n; r++) { float t = A_(r, i); ss += t * t; }
      float xnorm = sqrtf(ss);
      if (xnorm != 0.0f) {
        float beta = -sf_sign(slapy2(alpha, xnorm), alpha);
        taui = (beta - alpha) / beta;
        float sc = 1.0f / (alpha - beta);
#pragma unroll
        for (int r = i + 2; r <= n; r++) A_(r, i) *= sc;
        alpha = beta;
      }
    }
    E_(i) = alpha;
    A_(i + 1, i) = alpha;
    if (taui != 0.0f) {
      A_(i + 1, i) = 1.0f;
#pragma unroll
      for (int r = i + 1; r <= n; r++) {
        float s = 0.0f;
#pragma unroll
        for (int c = i + 1; c <= n; c++) {
          float arc = (r >= c) ? A_(r, c) : A_(c, r);
          s += arc * A_(c, i);
        }
        WV(r) = taui * s;
      }
      float dot = 0.0f;
#pragma unroll
      for (int r = i + 1; r <= n; r++) dot += WV(r) * A_(r, i);
      float al2 = -0.5f * taui * dot;
#pragma unroll
      for (int r = i + 1; r <= n; r++) WV(r) += al2 * A_(r, i);
#pragma unroll
      for (int c = i + 1; c <= n; c++)
#pragma unroll
        for (int r = c; r <= n; r++)
          A_(r, c) -= A_(r, i) * WV(c) + WV(r) * A_(c, i);
      A_(i + 1, i) = E_(i);
    }
    D_(i) = A_(i, i);
    TAUV(i) = taui;
  }
  D_(n) = A_(n, n);

  // -------- form Q0 = H(1)...H(n-1), all static --------
#pragma unroll
  for (int r = 1; r <= n; r++)
#pragma unroll
    for (int c = 1; c <= n; c++) Z_(r, c) = (r == c) ? 1.0f : 0.0f;
#pragma unroll
  for (int i = n - 1; i >= 1; i--) {
    float taui = TAUV(i);
    if (taui != 0.0f) {
#pragma unroll
      for (int c = 1; c <= n; c++) {
        float t = Z_(i + 1, c);
#pragma unroll
        for (int r = i + 2; r <= n; r++) t += A_(r, i) * Z_(r, c);
        t *= taui;
        Z_(i + 1, c) -= t;
#pragma unroll
        for (int r = i + 2; r <= n; r++) Z_(r, c) -= A_(r, i) * t;
      }
    }
  }

  // -------- ssteqr ('V'); fp32 constants are branch-critical -------------
  const float eps = 5.9604644775390625e-08f;      // 2^-24
  const float eps2 = eps * eps;
  const float safmin = 1.17549435082228751e-38f;  // 2^-126
  const int nmaxit = n * 30;
  int jtot = 0;
  int l1 = 1;
  int guard = 0;

  while (l1 <= n && guard++ < 2000) {
    int m;
    if (l1 > 1) put10(ev, l1 - 2, 0.0f);  // E_(l1-1) = 0
    {
      bool found = false;
      int mf = n;
#pragma unroll
      for (int k = 1; k <= n - 1; k++) {
        if (!found && k >= l1) {
          float tst = fabsf(ev[k - 1]);
          if (tst == 0.0f) {
            mf = k; found = true;
          } else if (tst <= (sqrtf(fabsf(dv[k - 1])) * sqrtf(fabsf(dv[k]))) * eps) {
            ev[k - 1] = 0.0f;  // static k
            mf = k; found = true;
          }
        }
      }
      m = found ? mf : n;
    }
    int l = l1, lsv = l, lend = m, lendsv = m;
    l1 = m + 1;
    if (lend == l) continue;
    if (fabsf(sel10(dv, lend - 1)) < fabsf(sel10(dv, l - 1))) { lend = lsv; l = lendsv; }

    if (lend > l) {
      // ---------------- QL iteration ----------------
      for (;;) {
        if (guard++ > 4000) break;
        int m2;
        if (l != lend) {
          bool found = false;
          int mf = lend;
#pragma unroll
          for (int k = 1; k <= n - 1; k++) {
            if (!found && k >= l && k <= lend - 1) {
              float tst = ev[k - 1] * ev[k - 1];
              if (tst <= (eps2 * fabsf(dv[k - 1])) * fabsf(dv[k]) + safmin) {
                mf = k; found = true;
              }
            }
          }
          m2 = found ? mf : lend;
        } else {
          m2 = lend;
        }
        if (m2 < lend) put10(ev, m2 - 1, 0.0f);
        float p = sel10(dv, l - 1);
        if (m2 == l) {  // eigenvalue found
          put10(dv, l - 1, p);
          l = l + 1;
          if (l <= lend) continue;
          break;
        }
        if (m2 == l + 1) {  // 2x2 block
          float rt1, rt2, c2, s2;
          slaev2(sel10(dv, l - 1), sel10(ev, l - 1), sel10(dv, l), &rt1, &rt2, &c2, &s2);
#pragma unroll
          for (int j = 1; j <= n - 1; j++) {
            if (j == l) {  // 0-based cols: (j) = 1-based l+1, (j-1) = 1-based l
#pragma unroll
              for (int r = 0; r < n; r++) {
                float t = Zm[r * 10 + j];
                Zm[r * 10 + j]     = c2 * t - s2 * Zm[r * 10 + j - 1];
                Zm[r * 10 + j - 1] = s2 * t + c2 * Zm[r * 10 + j - 1];
              }
            }
          }
          put10(dv, l - 1, rt1);
          put10(dv, l, rt2);
          put10(ev, l - 1, 0.0f);
          l = l + 2;
          if (l <= lend) continue;
          break;
        }
        if (jtot == nmaxit) break;
        jtot++;
        float El = sel10(ev, l - 1);
        float gg = (sel10(dv, l) - p) / (2.0f * El);
        float rr = slapy2(gg, 1.0f);
        gg = sel10(dv, m2 - 1) - p + (El / (gg + sf_sign(rr, gg)));
        float s = 1.0f, c = 1.0f;
        p = 0.0f;
#pragma unroll
        for (int i = n - 1; i >= 1; i--) {
          if (i <= m2 - 1 && i >= l) {
            float f = s * ev[i - 1];
            float b = c * ev[i - 1];
            slartg(gg, f, &c, &s, &rr);
            if (i != m2 - 1) ev[i] = rr;  // E_(i+1), static
            gg = dv[i] - p;               // D_(i+1)
            rr = (dv[i - 1] - gg) * s + 2.0f * c * b;
            p = s * rr;
            dv[i] = gg + p;
            gg = c * rr - b;
            csv[i - 1] = c;
            snv[i - 1] = -s;
          }
        }
        // slasr 'R','V','B': j = m2-1 down to l
#pragma unroll
        for (int j = n - 1; j >= 1; j--) {
          if (j <= m2 - 1 && j >= l) {
            float cj = csv[j - 1], sj = snv[j - 1];
#pragma unroll
            for (int r = 0; r < n; r++) {
              float t = Zm[r * 10 + j];
              Zm[r * 10 + j]     = cj * t - sj * Zm[r * 10 + j - 1];
              Zm[r * 10 + j - 1] = sj * t + cj * Zm[r * 10 + j - 1];
            }
          }
        }
        put10(dv, l - 1, sel10(dv, l - 1) - p);
        put10(ev, l - 1, gg);
      }
    } else {
      // ---------------- QR iteration ----------------
      for (;;) {
        if (guard++ > 4000) break;
        int m2;
        if (l != lend) {
          bool found = false;
          int mf = lend;
#pragma unroll
          for (int k = n; k >= 2; k--) {
            if (!found && k <= l && k >= lend + 1) {
              float tst = ev[k - 2] * ev[k - 2];
              if (tst <= (eps2 * fabsf(dv[k - 1])) * fabsf(dv[k - 2]) + safmin) {
                mf = k; found = true;
              }
            }
          }
          m2 = found ? mf : lend;
        } else {
          m2 = lend;
        }
        if (m2 > lend) put10(ev, m2 - 2, 0.0f);  // E_(m2-1) = 0
        float p = sel10(dv, l - 1);
        if (m2 == l) {  // eigenvalue found
          put10(dv, l - 1, p);
          l = l - 1;
          if (l >= lend) continue;
          break;
        }
        if (m2 == l - 1) {  // 2x2 block
          float rt1, rt2, c2, s2;
          slaev2(sel10(dv, l - 2), sel10(ev, l - 2), sel10(dv, l - 1), &rt1, &rt2, &c2, &s2);
#pragma unroll
          for (int j = 1; j <= n - 1; j++) {
            if (j == l - 1) {  // 0-based cols: (j) = 1-based l, (j-1) = 1-based l-1
#pragma unroll
              for (int r = 0; r < n; r++) {
                float t = Zm[r * 10 + j];
                Zm[r * 10 + j]     = c2 * t - s2 * Zm[r * 10 + j - 1];
                Zm[r * 10 + j - 1] = s2 * t + c2 * Zm[r * 10 + j - 1];
              }
            }
          }
          put10(dv, l - 2, rt1);
          put10(dv, l - 1, rt2);
          put10(ev, l - 2, 0.0f);
          l = l - 2;
          if (l >= lend) continue;
          break;
        }
        if (jtot == nmaxit) break;
        jtot++;
        float El1 = sel10(ev, l - 2);  // E_(l-1)
        float gg = (sel10(dv, l - 2) - p) / (2.0f * El1);
        float rr = slapy2(gg, 1.0f);
        gg = sel10(dv, m2 - 1) - p + (El1 / (gg + sf_sign(rr, gg)));
        float s = 1.0f, c = 1.0f;
        p = 0.0f;
#pragma unroll
        for (int i = 1; i <= n - 1; i++) {
          if (i >= m2 && i <= l - 1) {
            float f = s * ev[i - 1];
            float b = c * ev[i - 1];
            slartg(gg, f, &c, &s, &rr);
            if (i >= 2) {
              if (i != m2) ev[i - 2] = rr;  // E_(i-1), static
            }
            gg = dv[i - 1] - p;  // D_(i)
            rr = (dv[i] - gg) * s + 2.0f * c * b;
            p = s * rr;
            dv[i - 1] = gg + p;
            gg = c * rr - b;
            csv[i - 1] = c;
            snv[i - 1] = s;
          }
        }
        // slasr 'R','V','F': j = m2 .. l-1 ascending
#pragma unroll
        for (int j = 1; j <= n - 1; j++) {
          if (j >= m2 && j <= l - 1) {
            float cj = csv[j - 1], sj = snv[j - 1];
#pragma unroll
            for (int r = 0; r < n; r++) {
              float t = Zm[r * 10 + j];
              Zm[r * 10 + j]     = cj * t - sj * Zm[r * 10 + j - 1];
              Zm[r * 10 + j - 1] = sj * t + cj * Zm[r * 10 + j - 1];
            }
          }
        }
        put10(dv, l - 1, sel10(dv, l - 1) - p);
        put10(ev, l - 2, gg);  // E_(l-1)
      }
    }
  }

  // -------- selection sort ascending (as in ssteqr) --------
#pragma unroll
  for (int ii = 2; ii <= n; ii++) {
    const int i = ii - 1;  // static
    int k = i;
    float p = dv[i - 1];
#pragma unroll
    for (int j = ii; j <= n; j++) {
      if (dv[j - 1] < p) { k = j; p = dv[j - 1]; }
    }
    if (k != i) {
      float Di = dv[i - 1];
      put10(dv, k - 1, Di);
      dv[i - 1] = p;
#pragma unroll
      for (int kk = 1; kk <= n; kk++) {
        if (kk == k) {
#pragma unroll
          for (int r = 0; r < n; r++) {
            float t = Zm[r * 10 + (i - 1)];
            Zm[r * 10 + (i - 1)] = Zm[r * 10 + (kk - 1)];
            Zm[r * 10 + (kk - 1)] = t;
          }
        }
      }
    }
  }

  // -------- MLP: relu(w @ W1^T + b1) @ W2^T + b2 -> 0.5*(sigmoid+1) ------
#pragma unroll
  for (int r = 0; r < 10; r++) {
    double o = (double)b2[0];
#pragma unroll
    for (int h = 0; h < 16; h++) {
      double sgm = (double)b1[h];
#pragma unroll
      for (int k = 0; k < 10; k++) sgm += (double)Zm[r * 10 + k] * (double)W1[h * 10 + k];
      if (sgm > 0.0) o += sgm * (double)W2[h];
    }
    double sig = 1.0 / (1.0 + exp(-o));
    out[r] = (float)(0.5 * (sig + 1.0));
  }
}

extern "C" void kernel_launch(void* const* d_in, const int* in_sizes, int n_in,
                              void* d_out, int out_size, void* d_ws, size_t ws_size,
                              hipStream_t stream) {
  const float* x  = (const float*)d_in[0];
  const float* W1 = (const float*)d_in[1];
  const float* b1 = (const float*)d_in[2];
  const float* W2 = (const float*)d_in[3];
  const float* b2 = (const float*)d_in[4];
  double* g = (double*)d_ws;
  float* out = (float*)d_out;

  int nrows = in_sizes[0] / 10;
  int npairs = nrows / 2;

  zero_ws_kernel<<<1, 64, 0, stream>>>(g);
  gram_kernel<<<GRID2, BLK2, 0, stream>>>(x, g, npairs);
  eig_mlp_kernel<<<1, 64, 0, stream>>>(g, W1, b1, W2, b2, out);
}

// Round 4
// 367.076 us; speedup vs baseline: 1.4192x; 1.0298x over previous
//
#include <hip/hip_runtime.h>
#include <math.h>

// ---------------------------------------------------------------------------
// gram = x^T x (N=4M, D=10, fp64-accurate reduction) -> fp32 -> LAPACK-
// faithful fp32 ssyevd path (ssytd2 'L' + ssteqr, LAPACK>=3.10 slartg) -> MLP.
// Round 4:
//  * gram: LDS-staged so global loads are 16B/lane stride-1 coalesced
//    (round-3's 80B/thread stride pattern was uncoalesced); 4 atomic replicas.
//  * eig: round-3's icache/branch stall (VALUBusy 0.035%, FETCH 105KB of code)
//    fixed by compact dynamic loops: dv/ev/csv/snv in registers via sel10/
//    put10 (cndmask chains, no branches); Z lane-distributed (lane r = row r)
//    with carried-register rotation walks. Arithmetic order per element is
//    identical to the passing round-2/3 kernels.
// ---------------------------------------------------------------------------

#define BLK2 256
#define GRID2 1024
#define TILE_F4 (BLK2 * 5)  // 1280 float4 = 20KB = 512 rows per tile

__global__ void zero_ws_kernel(double* __restrict__ g) {
  int t = threadIdx.x;
  if (t < 220) g[t] = 0.0;
}

__global__ __launch_bounds__(BLK2) void gram_kernel(const float4* __restrict__ x4,
                                                    double* __restrict__ g,
                                                    int nf4) {
  __shared__ float4 tile[TILE_F4];
  float acc[55];
#pragma unroll
  for (int k = 0; k < 55; k++) acc[k] = 0.0f;

  const int tid = threadIdx.x;
  const int ntiles = (nf4 + TILE_F4 - 1) / TILE_F4;

  for (int t = blockIdx.x; t < ntiles; t += GRID2) {
    const int base = t * TILE_F4;
    float4 r0, r1, r2, r3, r4;
    {
      int i0 = base + 0 * BLK2 + tid;
      int i1 = base + 1 * BLK2 + tid;
      int i2 = base + 2 * BLK2 + tid;
      int i3 = base + 3 * BLK2 + tid;
      int i4 = base + 4 * BLK2 + tid;
      float4 zz = make_float4(0.f, 0.f, 0.f, 0.f);
      r0 = (i0 < nf4) ? x4[i0] : zz;
      r1 = (i1 < nf4) ? x4[i1] : zz;
      r2 = (i2 < nf4) ? x4[i2] : zz;
      r3 = (i3 < nf4) ? x4[i3] : zz;
      r4 = (i4 < nf4) ? x4[i4] : zz;
    }
    __syncthreads();  // previous iteration's reads complete
    tile[0 * BLK2 + tid] = r0;
    tile[1 * BLK2 + tid] = r1;
    tile[2 * BLK2 + tid] = r2;
    tile[3 * BLK2 + tid] = r3;
    tile[4 * BLK2 + tid] = r4;
    __syncthreads();
    float4 q0 = tile[tid * 5 + 0];
    float4 q1 = tile[tid * 5 + 1];
    float4 q2 = tile[tid * 5 + 2];
    float4 q3 = tile[tid * 5 + 3];
    float4 q4 = tile[tid * 5 + 4];
    float v[20] = {q0.x, q0.y, q0.z, q0.w, q1.x, q1.y, q1.z, q1.w,
                   q2.x, q2.y, q2.z, q2.w, q3.x, q3.y, q3.z, q3.w,
                   q4.x, q4.y, q4.z, q4.w};
    int k = 0;
#pragma unroll
    for (int i = 0; i < 10; i++) {
#pragma unroll
      for (int j = 0; j <= i; j++) {
        acc[k] += v[i] * v[j] + v[10 + i] * v[10 + j];
        k++;
      }
    }
  }

  __shared__ double sred[4][55];
  int lane = threadIdx.x & 63;
  int wv = threadIdx.x >> 6;
#pragma unroll
  for (int k = 0; k < 55; k++) {
    double d = (double)acc[k];
#pragma unroll
    for (int off = 32; off > 0; off >>= 1) d += __shfl_down(d, off, 64);
    if (lane == 0) sred[wv][k] = d;
  }
  __syncthreads();
  double* gr = g + 55 * (blockIdx.x & 3);  // 4 replicas -> 4x fewer per-address atomics
  if (threadIdx.x < 55) {
    double s = sred[0][threadIdx.x] + sred[1][threadIdx.x] +
               sred[2][threadIdx.x] + sred[3][threadIdx.x];
    atomicAdd(&gr[threadIdx.x], s);
  }
}

// ------------------------- LAPACK helpers (fp32) ---------------------------

__device__ __forceinline__ float sf_sign(float a, float b) {
  return (b >= 0.0f) ? fabsf(a) : -fabsf(a);
}

__device__ __forceinline__ float slapy2(float x, float y) {
  float xa = fabsf(x), ya = fabsf(y);
  float w = fmaxf(xa, ya), z = fminf(xa, ya);
  if (z == 0.0f) return w;
  float q = z / w;
  return w * sqrtf(1.0f + q * q);
}

// LAPACK >= 3.10 slartg: c = |f|/d >= 0, r = sign(f)*d, s = g/r
__device__ __forceinline__ void slartg(float f, float g, float* c, float* s, float* r) {
  if (g == 0.0f) {
    *c = 1.0f; *s = 0.0f; *r = f;
  } else if (f == 0.0f) {
    *c = 0.0f; *s = sf_sign(1.0f, g); *r = fabsf(g);
  } else {
    float d = sqrtf(f * f + g * g);
    *c = fabsf(f) / d;
    float rr = sf_sign(d, f);
    *s = g / rr;
    *r = rr;
  }
}

__device__ __forceinline__ void slaev2(float a, float b, float c,
                                       float* rt1, float* rt2, float* cs1, float* sn1) {
  float sm = a + c;
  float df = a - c;
  float adf = fabsf(df);
  float tb = b + b;
  float ab = fabsf(tb);
  float acmx, acmn;
  if (fabsf(a) > fabsf(c)) { acmx = a; acmn = c; } else { acmx = c; acmn = a; }
  float rt;
  if (adf > ab)      { float t = ab / adf; rt = adf * sqrtf(1.0f + t * t); }
  else if (adf < ab) { float t = adf / ab; rt = ab * sqrtf(1.0f + t * t); }
  else               { rt = ab * sqrtf(2.0f); }
  int sgn1;
  if (sm < 0.0f) {
    *rt1 = 0.5f * (sm - rt); sgn1 = -1;
    *rt2 = (acmx / *rt1) * acmn - (b / *rt1) * b;
  } else if (sm > 0.0f) {
    *rt1 = 0.5f * (sm + rt); sgn1 = 1;
    *rt2 = (acmx / *rt1) * acmn - (b / *rt1) * b;
  } else {
    *rt1 = 0.5f * rt; *rt2 = -0.5f * rt; sgn1 = 1;
  }
  int sgn2;
  float cs;
  if (df >= 0.0f) { cs = df + rt; sgn2 = 1; } else { cs = df - rt; sgn2 = -1; }
  float acs = fabsf(cs);
  if (acs > ab) {
    float ct = -tb / cs;
    *sn1 = 1.0f / sqrtf(1.0f + ct * ct);
    *cs1 = ct * (*sn1);
  } else {
    if (ab == 0.0f) { *cs1 = 1.0f; *sn1 = 0.0f; }
    else {
      float tn = -cs / tb;
      *cs1 = 1.0f / sqrtf(1.0f + tn * tn);
      *sn1 = tn * (*cs1);
    }
  }
  if (sgn1 == sgn2) { float tn = *cs1; *cs1 = -(*sn1); *sn1 = tn; }
}

// 10-way register select / masked write (runtime idx0, 0-based); branch-free
__device__ __forceinline__ float sel10(const float* a, int idx0) {
  float v = 0.0f;
#pragma unroll
  for (int k = 0; k < 10; k++) v = (k == idx0) ? a[k] : v;
  return v;
}
__device__ __forceinline__ void put10(float* a, int idx0, float v) {
#pragma unroll
  for (int k = 0; k < 10; k++) a[k] = (k == idx0) ? v : a[k];
}

// static 1-based access macros (indices must be compile-time constants)
#define A_(r, c) Am[((r)-1) * 10 + ((c)-1)]
#define Z_(r, c) Zm[((r)-1) * 10 + ((c)-1)]
#define D_(i) dv[(i)-1]
#define E_(i) ev[(i)-1]
#define TAUV(i) tauv[(i)-1]
#define WV(i) wvv[(i)-1]

__global__ __launch_bounds__(64, 1) void eig_mlp_kernel(
    const double* __restrict__ g,
    const float* __restrict__ W1,
    const float* __restrict__ b1,
    const float* __restrict__ W2,
    const float* __restrict__ b2,
    float* __restrict__ out) {
  if (blockIdx.x != 0) return;
  const int lane = threadIdx.x;
  const int n = 10;
  float Am[100], Zm[100];
  float dv[10], ev[10], tauv[10], wvv[10], csv[10], snv[10];

  // load gram (4 replicas summed in fp64), round to fp32 — uniform on all lanes
  {
    int k = 0;
#pragma unroll
    for (int i = 0; i < 10; i++)
#pragma unroll
      for (int j = 0; j <= i; j++) {
        double v = g[k] + g[55 + k] + g[110 + k] + g[165 + k];
        float f = (float)v;
        Am[i * 10 + j] = f;
        Am[j * 10 + i] = f;
        k++;
      }
  }

  // -------- ssytd2 (UPLO='L'), static, register-resident, uniform --------
#pragma unroll
  for (int i = 1; i <= n - 1; i++) {
    const int nmi = n - i;
    float alpha = A_(i + 1, i);
    float taui = 0.0f;
    if (nmi > 1) {
      float ss = 0.0f;
#pragma unroll
      for (int r = i + 2; r <= n; r++) { float t = A_(r, i); ss += t * t; }
      float xnorm = sqrtf(ss);
      if (xnorm != 0.0f) {
        float beta = -sf_sign(slapy2(alpha, xnorm), alpha);
        taui = (beta - alpha) / beta;
        float sc = 1.0f / (alpha - beta);
#pragma unroll
        for (int r = i + 2; r <= n; r++) A_(r, i) *= sc;
        alpha = beta;
      }
    }
    E_(i) = alpha;
    A_(i + 1, i) = alpha;
    if (taui != 0.0f) {
      A_(i + 1, i) = 1.0f;
#pragma unroll
      for (int r = i + 1; r <= n; r++) {
        float s = 0.0f;
#pragma unroll
        for (int c = i + 1; c <= n; c++) {
          float arc = (r >= c) ? A_(r, c) : A_(c, r);
          s += arc * A_(c, i);
        }
        WV(r) = taui * s;
      }
      float dot = 0.0f;
#pragma unroll
      for (int r = i + 1; r <= n; r++) dot += WV(r) * A_(r, i);
      float al2 = -0.5f * taui * dot;
#pragma unroll
      for (int r = i + 1; r <= n; r++) WV(r) += al2 * A_(r, i);
#pragma unroll
      for (int c = i + 1; c <= n; c++)
#pragma unroll
        for (int r = c; r <= n; r++)
          A_(r, c) -= A_(r, i) * WV(c) + WV(r) * A_(c, i);
      A_(i + 1, i) = E_(i);
    }
    D_(i) = A_(i, i);
    TAUV(i) = taui;
  }
  D_(n) = A_(n, n);

  // -------- form Q0 = H(1)...H(n-1), static, uniform --------
#pragma unroll
  for (int r = 1; r <= n; r++)
#pragma unroll
    for (int c = 1; c <= n; c++) Z_(r, c) = (r == c) ? 1.0f : 0.0f;
#pragma unroll
  for (int i = n - 1; i >= 1; i--) {
    float taui = TAUV(i);
    if (taui != 0.0f) {
#pragma unroll
      for (int c = 1; c <= n; c++) {
        float t = Z_(i + 1, c);
#pragma unroll
        for (int r = i + 2; r <= n; r++) t += A_(r, i) * Z_(r, c);
        t *= taui;
        Z_(i + 1, c) -= t;
#pragma unroll
        for (int r = i + 2; r <= n; r++) Z_(r, c) -= A_(r, i) * t;
      }
    }
  }

  // -------- distribute Z rows: lane r holds row r as z[0..9] --------
  const int r_own = (lane < 10) ? lane : 0;
  float z[10];
#pragma unroll
  for (int k = 0; k < 10; k++) {
    float v = Zm[0 * 10 + k];
#pragma unroll
    for (int rr = 1; rr < 10; rr++) v = (r_own == rr) ? Zm[rr * 10 + k] : v;
    z[k] = v;
  }

  // -------- ssteqr ('V'), compact dynamic loops, uniform control ----------
  const float eps = 5.9604644775390625e-08f;      // 2^-24
  const float eps2 = eps * eps;
  const float safmin = 1.17549435082228751e-38f;  // 2^-126
  const int nmaxit = n * 30;
  int jtot = 0;
  int l1 = 1;
  int guard = 0;

  while (l1 <= n && guard++ < 2000) {
    if (l1 > 1) put10(ev, l1 - 2, 0.0f);  // E_(l1-1) = 0
    int m = n;
    for (int mm = l1; mm <= n - 1; mm++) {
      float tst = fabsf(sel10(ev, mm - 1));
      if (tst == 0.0f) { m = mm; break; }
      if (tst <= (sqrtf(fabsf(sel10(dv, mm - 1))) * sqrtf(fabsf(sel10(dv, mm)))) * eps) {
        put10(ev, mm - 1, 0.0f);
        m = mm;
        break;
      }
    }
    int l = l1, lsv = l, lend = m, lendsv = m;
    l1 = m + 1;
    if (lend == l) continue;
    if (fabsf(sel10(dv, lend - 1)) < fabsf(sel10(dv, l - 1))) { lend = lsv; l = lendsv; }

    if (lend > l) {
      // ---------------- QL iteration ----------------
      for (;;) {
        if (guard++ > 4000) break;
        int m2 = lend;
        if (l != lend) {
          for (int mm = l; mm <= lend - 1; mm++) {
            float e = sel10(ev, mm - 1);
            if (e * e <= (eps2 * fabsf(sel10(dv, mm - 1))) * fabsf(sel10(dv, mm)) + safmin) {
              m2 = mm;
              break;
            }
          }
        }
        if (m2 < lend) put10(ev, m2 - 1, 0.0f);
        float p = sel10(dv, l - 1);
        if (m2 == l) {  // eigenvalue found
          put10(dv, l - 1, p);
          l = l + 1;
          if (l <= lend) continue;
          break;
        }
        if (m2 == l + 1) {  // 2x2 block; 0-based cols (l, l-1)
          float rt1, rt2, c2, s2;
          slaev2(sel10(dv, l - 1), sel10(ev, l - 1), sel10(dv, l), &rt1, &rt2, &c2, &s2);
          float a = sel10(z, l);
          float b = sel10(z, l - 1);
          put10(z, l, c2 * a - s2 * b);
          put10(z, l - 1, s2 * a + c2 * b);
          put10(dv, l - 1, rt1);
          put10(dv, l, rt2);
          put10(ev, l - 1, 0.0f);
          l = l + 2;
          if (l <= lend) continue;
          break;
        }
        if (jtot == nmaxit) break;
        jtot++;
        float El = sel10(ev, l - 1);
        float gg = (sel10(dv, l) - p) / (2.0f * El);
        float rr = slapy2(gg, 1.0f);
        gg = sel10(dv, m2 - 1) - p + (El / (gg + sf_sign(rr, gg)));
        float s = 1.0f, c = 1.0f;
        p = 0.0f;
        for (int i = m2 - 1; i >= l; i--) {
          float e = sel10(ev, i - 1);
          float f = s * e, b = c * e;
          slartg(gg, f, &c, &s, &rr);
          if (i != m2 - 1) put10(ev, i, rr);  // E_(i+1)
          gg = sel10(dv, i) - p;              // D_(i+1)
          rr = (sel10(dv, i - 1) - gg) * s + 2.0f * c * b;
          p = s * rr;
          put10(dv, i, gg + p);
          gg = c * rr - b;
          put10(csv, i - 1, c);
          put10(snv, i - 1, -s);
        }
        // apply rotations (slasr 'B'): descending j = m2-1..l, 0-based cols (j, j-1)
        {
          float a = sel10(z, m2 - 1);  // carried updated value of col j
          for (int j = m2 - 1; j >= l; j--) {
            float cj = sel10(csv, j - 1), sj = sel10(snv, j - 1);
            float b = sel10(z, j - 1);      // untouched original
            put10(z, j, cj * a - sj * b);   // final col j
            a = sj * a + cj * b;            // new col j-1, carried
          }
          put10(z, l - 1, a);
        }
        put10(dv, l - 1, sel10(dv, l - 1) - p);
        put10(ev, l - 1, gg);
      }
    } else {
      // ---------------- QR iteration ----------------
      for (;;) {
        if (guard++ > 4000) break;
        int m2 = lend;
        if (l != lend) {
          for (int mm = l; mm >= lend + 1; mm--) {
            float e = sel10(ev, mm - 2);
            if (e * e <= (eps2 * fabsf(sel10(dv, mm - 1))) * fabsf(sel10(dv, mm - 2)) + safmin) {
              m2 = mm;
              break;
            }
          }
        }
        if (m2 > lend) put10(ev, m2 - 2, 0.0f);  // E_(m2-1) = 0
        float p = sel10(dv, l - 1);
        if (m2 == l) {  // eigenvalue found
          put10(dv, l - 1, p);
          l = l - 1;
          if (l >= lend) continue;
          break;
        }
        if (m2 == l - 1) {  // 2x2 block; 0-based cols (l-1, l-2)
          float rt1, rt2, c2, s2;
          slaev2(sel10(dv, l - 2), sel10(ev, l - 2), sel10(dv, l - 1), &rt1, &rt2, &c2, &s2);
          float a = sel10(z, l - 1);
          float b = sel10(z, l - 2);
          put10(z, l - 1, c2 * a - s2 * b);
          put10(z, l - 2, s2 * a + c2 * b);
          put10(dv, l - 2, rt1);
          put10(dv, l - 1, rt2);
          put10(ev, l - 2, 0.0f);
          l = l - 2;
          if (l >= lend) continue;
          break;
        }
        if (jtot == nmaxit) break;
        jtot++;
        float El1 = sel10(ev, l - 2);  // E_(l-1)
        float gg = (sel10(dv, l - 2) - p) / (2.0f * El1);
        float rr = slapy2(gg, 1.0f);
        gg = sel10(dv, m2 - 1) - p + (El1 / (gg + sf_sign(rr, gg)));
        float s = 1.0f, c = 1.0f;
        p = 0.0f;
        for (int i = m2; i <= l - 1; i++) {
          float e = sel10(ev, i - 1);
          float f = s * e, b = c * e;
          slartg(gg, f, &c, &s, &rr);
          if (i != m2) put10(ev, i - 2, rr);  // E_(i-1)
          gg = sel10(dv, i - 1) - p;          // D_(i)
          rr = (sel10(dv, i) - gg) * s + 2.0f * c * b;
          p = s * rr;
          put10(dv, i - 1, gg + p);
          gg = c * rr - b;
          put10(csv, i - 1, c);
          put10(snv, i - 1, s);
        }
        // apply rotations (slasr 'F'): ascending j = m2..l-1, 0-based cols (j, j-1)
        {
          float carry = sel10(z, m2 - 1);  // current value of col j-1
          for (int j = m2; j <= l - 1; j++) {
            float cj = sel10(csv, j - 1), sj = sel10(snv, j - 1);
            float t = sel10(z, j);                 // untouched original
            put10(z, j - 1, sj * t + cj * carry);  // final col j-1
            carry = cj * t - sj * carry;           // new col j, carried
          }
          put10(z, l - 1, carry);
        }
        put10(dv, l - 1, sel10(dv, l - 1) - p);
        put10(ev, l - 2, gg);  // E_(l-1)
      }
    }
  }

  // -------- selection sort ascending (as in ssteqr), uniform --------
  for (int ii = 2; ii <= n; ii++) {
    int i = ii - 1;
    int k = i;
    float p = sel10(dv, i - 1);
    for (int j = ii; j <= n; j++) {
      float dj = sel10(dv, j - 1);
      if (dj < p) { k = j; p = dj; }
    }
    if (k != i) {
      float di = sel10(dv, i - 1);
      put10(dv, k - 1, di);
      put10(dv, i - 1, p);
      float a = sel10(z, i - 1), b = sel10(z, k - 1);
      put10(z, i - 1, b);
      put10(z, k - 1, a);
    }
  }

  // -------- MLP per lane (lane r computes output row r) --------
  if (lane < 10) {
    double o = (double)b2[0];
#pragma unroll
    for (int h = 0; h < 16; h++) {
      double sgm = (double)b1[h];
#pragma unroll
      for (int k = 0; k < 10; k++) sgm += (double)z[k] * (double)W1[h * 10 + k];
      if (sgm > 0.0) o += sgm * (double)W2[h];
    }
    double sig = 1.0 / (1.0 + exp(-o));
    out[lane] = (float)(0.5 * (sig + 1.0));
  }
}

extern "C" void kernel_launch(void* const* d_in, const int* in_sizes, int n_in,
                              void* d_out, int out_size, void* d_ws, size_t ws_size,
                              hipStream_t stream) {
  const float* x  = (const float*)d_in[0];
  const float* W1 = (const float*)d_in[1];
  const float* b1 = (const float*)d_in[2];
  const float* W2 = (const float*)d_in[3];
  const float* b2 = (const float*)d_in[4];
  double* g = (double*)d_ws;
  float* out = (float*)d_out;

  int nf4 = in_sizes[0] / 4;  // 10M float4

  zero_ws_kernel<<<1, 256, 0, stream>>>(g);
  gram_kernel<<<GRID2, BLK2, 0, stream>>>((const float4*)x, g, nf4);
  eig_mlp_kernel<<<1, 64, 0, stream>>>(g, W1, b1, W2, b2, out);
}

// Round 5
// 339.469 us; speedup vs baseline: 1.5346x; 1.0813x over previous
//
#include <hip/hip_runtime.h>
#include <math.h>

// ---------------------------------------------------------------------------
// gram = x^T x (N=4M, D=10, fp64-accurate reduction) -> fp32 -> LAPACK-
// faithful fp32 ssyevd path (ssytd2 'L' + ssteqr, LAPACK>=3.10 slartg) -> MLP.
// Round 5 (eig): hybrid of rounds 3+4 —
//  * ssteqr hot sweeps (deflation scans, rotation recurrence, z-apply) are
//    statically unrolled 9x with wave-uniform scalar range guards, so every
//    array index is compile-time -> pure register access, no cndmask chains
//    (round 4 spent ~80% of its instrs in sel10/put10 10-deep selects).
//  * z stays lane-distributed (10 regs/lane; round 3's 100-reg Zm unrolls
//    were the icache blowup). sel10/put10 only in once-per-sweep spots and
//    rare paths (2x2 blocks, final sort).
// Arithmetic op sequence per element is identical to passing rounds 2-4.
// ---------------------------------------------------------------------------

#define BLK2 256
#define GRID2 1024
#define TILE_F4 (BLK2 * 5)  // 1280 float4 = 20KB = 512 rows per tile

__global__ void zero_ws_kernel(double* __restrict__ g) {
  int t = threadIdx.x;
  if (t < 220) g[t] = 0.0;
}

__global__ __launch_bounds__(BLK2) void gram_kernel(const float4* __restrict__ x4,
                                                    double* __restrict__ g,
                                                    int nf4) {
  __shared__ float4 tile[TILE_F4];
  float acc[55];
#pragma unroll
  for (int k = 0; k < 55; k++) acc[k] = 0.0f;

  const int tid = threadIdx.x;
  const int ntiles = (nf4 + TILE_F4 - 1) / TILE_F4;

  for (int t = blockIdx.x; t < ntiles; t += GRID2) {
    const int base = t * TILE_F4;
    float4 r0, r1, r2, r3, r4;
    {
      int i0 = base + 0 * BLK2 + tid;
      int i1 = base + 1 * BLK2 + tid;
      int i2 = base + 2 * BLK2 + tid;
      int i3 = base + 3 * BLK2 + tid;
      int i4 = base + 4 * BLK2 + tid;
      float4 zz = make_float4(0.f, 0.f, 0.f, 0.f);
      r0 = (i0 < nf4) ? x4[i0] : zz;
      r1 = (i1 < nf4) ? x4[i1] : zz;
      r2 = (i2 < nf4) ? x4[i2] : zz;
      r3 = (i3 < nf4) ? x4[i3] : zz;
      r4 = (i4 < nf4) ? x4[i4] : zz;
    }
    __syncthreads();  // previous iteration's reads complete
    tile[0 * BLK2 + tid] = r0;
    tile[1 * BLK2 + tid] = r1;
    tile[2 * BLK2 + tid] = r2;
    tile[3 * BLK2 + tid] = r3;
    tile[4 * BLK2 + tid] = r4;
    __syncthreads();
    float4 q0 = tile[tid * 5 + 0];
    float4 q1 = tile[tid * 5 + 1];
    float4 q2 = tile[tid * 5 + 2];
    float4 q3 = tile[tid * 5 + 3];
    float4 q4 = tile[tid * 5 + 4];
    float v[20] = {q0.x, q0.y, q0.z, q0.w, q1.x, q1.y, q1.z, q1.w,
                   q2.x, q2.y, q2.z, q2.w, q3.x, q3.y, q3.z, q3.w,
                   q4.x, q4.y, q4.z, q4.w};
    int k = 0;
#pragma unroll
    for (int i = 0; i < 10; i++) {
#pragma unroll
      for (int j = 0; j <= i; j++) {
        acc[k] += v[i] * v[j] + v[10 + i] * v[10 + j];
        k++;
      }
    }
  }

  __shared__ double sred[4][55];
  int lane = threadIdx.x & 63;
  int wv = threadIdx.x >> 6;
#pragma unroll
  for (int k = 0; k < 55; k++) {
    double d = (double)acc[k];
#pragma unroll
    for (int off = 32; off > 0; off >>= 1) d += __shfl_down(d, off, 64);
    if (lane == 0) sred[wv][k] = d;
  }
  __syncthreads();
  double* gr = g + 55 * (blockIdx.x & 3);  // 4 replicas -> 4x fewer per-address atomics
  if (threadIdx.x < 55) {
    double s = sred[0][threadIdx.x] + sred[1][threadIdx.x] +
               sred[2][threadIdx.x] + sred[3][threadIdx.x];
    atomicAdd(&gr[threadIdx.x], s);
  }
}

// ------------------------- LAPACK helpers (fp32) ---------------------------

__device__ __forceinline__ float sf_sign(float a, float b) {
  return (b >= 0.0f) ? fabsf(a) : -fabsf(a);
}

__device__ __forceinline__ float slapy2(float x, float y) {
  float xa = fabsf(x), ya = fabsf(y);
  float w = fmaxf(xa, ya), z = fminf(xa, ya);
  if (z == 0.0f) return w;
  float q = z / w;
  return w * sqrtf(1.0f + q * q);
}

// LAPACK >= 3.10 slartg: c = |f|/d >= 0, r = sign(f)*d, s = g/r
__device__ __forceinline__ void slartg(float f, float g, float* c, float* s, float* r) {
  if (g == 0.0f) {
    *c = 1.0f; *s = 0.0f; *r = f;
  } else if (f == 0.0f) {
    *c = 0.0f; *s = sf_sign(1.0f, g); *r = fabsf(g);
  } else {
    float d = sqrtf(f * f + g * g);
    *c = fabsf(f) / d;
    float rr = sf_sign(d, f);
    *s = g / rr;
    *r = rr;
  }
}

__device__ __forceinline__ void slaev2(float a, float b, float c,
                                       float* rt1, float* rt2, float* cs1, float* sn1) {
  float sm = a + c;
  float df = a - c;
  float adf = fabsf(df);
  float tb = b + b;
  float ab = fabsf(tb);
  float acmx, acmn;
  if (fabsf(a) > fabsf(c)) { acmx = a; acmn = c; } else { acmx = c; acmn = a; }
  float rt;
  if (adf > ab)      { float t = ab / adf; rt = adf * sqrtf(1.0f + t * t); }
  else if (adf < ab) { float t = adf / ab; rt = ab * sqrtf(1.0f + t * t); }
  else               { rt = ab * sqrtf(2.0f); }
  int sgn1;
  if (sm < 0.0f) {
    *rt1 = 0.5f * (sm - rt); sgn1 = -1;
    *rt2 = (acmx / *rt1) * acmn - (b / *rt1) * b;
  } else if (sm > 0.0f) {
    *rt1 = 0.5f * (sm + rt); sgn1 = 1;
    *rt2 = (acmx / *rt1) * acmn - (b / *rt1) * b;
  } else {
    *rt1 = 0.5f * rt; *rt2 = -0.5f * rt; sgn1 = 1;
  }
  int sgn2;
  float cs;
  if (df >= 0.0f) { cs = df + rt; sgn2 = 1; } else { cs = df - rt; sgn2 = -1; }
  float acs = fabsf(cs);
  if (acs > ab) {
    float ct = -tb / cs;
    *sn1 = 1.0f / sqrtf(1.0f + ct * ct);
    *cs1 = ct * (*sn1);
  } else {
    if (ab == 0.0f) { *cs1 = 1.0f; *sn1 = 0.0f; }
    else {
      float tn = -cs / tb;
      *cs1 = 1.0f / sqrtf(1.0f + tn * tn);
      *sn1 = tn * (*cs1);
    }
  }
  if (sgn1 == sgn2) { float tn = *cs1; *cs1 = -(*sn1); *sn1 = tn; }
}

// 10-way register select / masked write (runtime idx0, 0-based); branch-free.
// Used ONLY outside hot loops (once-per-sweep spots, 2x2 blocks, sort).
__device__ __forceinline__ float sel10(const float* a, int idx0) {
  float v = 0.0f;
#pragma unroll
  for (int k = 0; k < 10; k++) v = (k == idx0) ? a[k] : v;
  return v;
}
__device__ __forceinline__ void put10(float* a, int idx0, float v) {
#pragma unroll
  for (int k = 0; k < 10; k++) a[k] = (k == idx0) ? v : a[k];
}

// static 1-based access macros (indices must be compile-time constants)
#define A_(r, c) Am[((r)-1) * 10 + ((c)-1)]
#define Z_(r, c) Zm[((r)-1) * 10 + ((c)-1)]
#define D_(i) dv[(i)-1]
#define E_(i) ev[(i)-1]
#define TAUV(i) tauv[(i)-1]
#define WV(i) wvv[(i)-1]

__global__ __launch_bounds__(64, 1) void eig_mlp_kernel(
    const double* __restrict__ g,
    const float* __restrict__ W1,
    const float* __restrict__ b1,
    const float* __restrict__ W2,
    const float* __restrict__ b2,
    float* __restrict__ out) {
  if (blockIdx.x != 0) return;
  const int lane = threadIdx.x;
  const int n = 10;
  float Am[100], Zm[100];
  float dv[10], ev[10], tauv[10], wvv[10], csv[10], snv[10];

  // load gram (4 replicas summed in fp64), round to fp32 — uniform on all lanes
  {
    int k = 0;
#pragma unroll
    for (int i = 0; i < 10; i++)
#pragma unroll
      for (int j = 0; j <= i; j++) {
        double v = g[k] + g[55 + k] + g[110 + k] + g[165 + k];
        float f = (float)v;
        Am[i * 10 + j] = f;
        Am[j * 10 + i] = f;
        k++;
      }
  }

  // -------- ssytd2 (UPLO='L'), static, register-resident, uniform --------
#pragma unroll
  for (int i = 1; i <= n - 1; i++) {
    const int nmi = n - i;
    float alpha = A_(i + 1, i);
    float taui = 0.0f;
    if (nmi > 1) {
      float ss = 0.0f;
#pragma unroll
      for (int r = i + 2; r <= n; r++) { float t = A_(r, i); ss += t * t; }
      float xnorm = sqrtf(ss);
      if (xnorm != 0.0f) {
        float beta = -sf_sign(slapy2(alpha, xnorm), alpha);
        taui = (beta - alpha) / beta;
        float sc = 1.0f / (alpha - beta);
#pragma unroll
        for (int r = i + 2; r <= n; r++) A_(r, i) *= sc;
        alpha = beta;
      }
    }
    E_(i) = alpha;
    A_(i + 1, i) = alpha;
    if (taui != 0.0f) {
      A_(i + 1, i) = 1.0f;
#pragma unroll
      for (int r = i + 1; r <= n; r++) {
        float s = 0.0f;
#pragma unroll
        for (int c = i + 1; c <= n; c++) {
          float arc = (r >= c) ? A_(r, c) : A_(c, r);
          s += arc * A_(c, i);
        }
        WV(r) = taui * s;
      }
      float dot = 0.0f;
#pragma unroll
      for (int r = i + 1; r <= n; r++) dot += WV(r) * A_(r, i);
      float al2 = -0.5f * taui * dot;
#pragma unroll
      for (int r = i + 1; r <= n; r++) WV(r) += al2 * A_(r, i);
#pragma unroll
      for (int c = i + 1; c <= n; c++)
#pragma unroll
        for (int r = c; r <= n; r++)
          A_(r, c) -= A_(r, i) * WV(c) + WV(r) * A_(c, i);
      A_(i + 1, i) = E_(i);
    }
    D_(i) = A_(i, i);
    TAUV(i) = taui;
  }
  D_(n) = A_(n, n);

  // -------- form Q0 = H(1)...H(n-1), static, uniform --------
#pragma unroll
  for (int r = 1; r <= n; r++)
#pragma unroll
    for (int c = 1; c <= n; c++) Z_(r, c) = (r == c) ? 1.0f : 0.0f;
#pragma unroll
  for (int i = n - 1; i >= 1; i--) {
    float taui = TAUV(i);
    if (taui != 0.0f) {
#pragma unroll
      for (int c = 1; c <= n; c++) {
        float t = Z_(i + 1, c);
#pragma unroll
        for (int r = i + 2; r <= n; r++) t += A_(r, i) * Z_(r, c);
        t *= taui;
        Z_(i + 1, c) -= t;
#pragma unroll
        for (int r = i + 2; r <= n; r++) Z_(r, c) -= A_(r, i) * t;
      }
    }
  }

  // -------- distribute Z rows: lane r holds row r as z[0..9] --------
  const int r_own = (lane < 10) ? lane : 0;
  float z[10];
#pragma unroll
  for (int k = 0; k < 10; k++) {
    float v = Zm[0 * 10 + k];
#pragma unroll
    for (int rr = 1; rr < 10; rr++) v = (r_own == rr) ? Zm[rr * 10 + k] : v;
    z[k] = v;
  }

  // -------- ssteqr ('V'); sweeps statically unrolled w/ range guards ------
  const float eps = 5.9604644775390625e-08f;      // 2^-24
  const float eps2 = eps * eps;
  const float safmin = 1.17549435082228751e-38f;  // 2^-126
  const int nmaxit = n * 30;
  int jtot = 0;
  int l1 = 1;
  int guard = 0;

  while (l1 <= n && guard++ < 2000) {
    if (l1 > 1) put10(ev, l1 - 2, 0.0f);  // E_(l1-1) = 0
    int m = n;
    {
      bool found = false;
#pragma unroll
      for (int k = 1; k <= n - 1; k++) {
        if (!found && k >= l1) {
          float tst = fabsf(ev[k - 1]);
          if (tst == 0.0f) {
            m = k; found = true;
          } else if (tst <= (sqrtf(fabsf(dv[k - 1])) * sqrtf(fabsf(dv[k]))) * eps) {
            ev[k - 1] = 0.0f;
            m = k; found = true;
          }
        }
      }
    }
    int l = l1, lsv = l, lend = m, lendsv = m;
    l1 = m + 1;
    if (lend == l) continue;
    if (fabsf(sel10(dv, lend - 1)) < fabsf(sel10(dv, l - 1))) { lend = lsv; l = lendsv; }

    if (lend > l) {
      // ---------------- QL iteration ----------------
      for (;;) {
        if (guard++ > 4000) break;
        int m2 = lend;
        if (l != lend) {
          bool fnd = false;
#pragma unroll
          for (int k = 1; k <= n - 1; k++) {
            if (!fnd && k >= l && k <= lend - 1) {
              float e = ev[k - 1];
              if (e * e <= (eps2 * fabsf(dv[k - 1])) * fabsf(dv[k]) + safmin) {
                m2 = k; fnd = true;
              }
            }
          }
        }
        if (m2 < lend) put10(ev, m2 - 1, 0.0f);
        float p = sel10(dv, l - 1);
        if (m2 == l) {  // eigenvalue found
          put10(dv, l - 1, p);
          l = l + 1;
          if (l <= lend) continue;
          break;
        }
        if (m2 == l + 1) {  // 2x2 block; 0-based cols (l, l-1)
          float rt1, rt2, c2, s2;
          slaev2(sel10(dv, l - 1), sel10(ev, l - 1), sel10(dv, l), &rt1, &rt2, &c2, &s2);
          float a = sel10(z, l);
          float b = sel10(z, l - 1);
          put10(z, l, c2 * a - s2 * b);
          put10(z, l - 1, s2 * a + c2 * b);
          put10(dv, l - 1, rt1);
          put10(dv, l, rt2);
          put10(ev, l - 1, 0.0f);
          l = l + 2;
          if (l <= lend) continue;
          break;
        }
        if (jtot == nmaxit) break;
        jtot++;
        float El = sel10(ev, l - 1);
        float gg = (sel10(dv, l) - p) / (2.0f * El);
        float rr = slapy2(gg, 1.0f);
        gg = sel10(dv, m2 - 1) - p + (El / (gg + sf_sign(rr, gg)));
        float s = 1.0f, c = 1.0f;
        p = 0.0f;
        // rotation recurrence, static descending unroll w/ scalar guards
#pragma unroll
        for (int i = n - 1; i >= 1; i--) {
          if (i <= m2 - 1 && i >= l) {
            float e = ev[i - 1];
            float f = s * e, b = c * e;
            slartg(gg, f, &c, &s, &rr);
            if (i != m2 - 1) ev[i] = rr;  // E_(i+1), static
            gg = dv[i] - p;               // D_(i+1)
            rr = (dv[i - 1] - gg) * s + 2.0f * c * b;
            p = s * rr;
            dv[i] = gg + p;
            gg = c * rr - b;
            csv[i - 1] = c;
            snv[i - 1] = -s;
          }
        }
        // apply rotations (slasr 'B'): descending j, 0-based cols (j, j-1)
        {
          float a = sel10(z, m2 - 1);  // carried updated value of col j
#pragma unroll
          for (int j = n - 1; j >= 1; j--) {
            if (j <= m2 - 1 && j >= l) {
              float cj = csv[j - 1], sj = snv[j - 1];  // static
              float b = z[j - 1];                      // untouched original
              z[j] = cj * a - sj * b;                  // final col j
              a = sj * a + cj * b;                     // new col j-1, carried
            }
          }
          put10(z, l - 1, a);
        }
        put10(dv, l - 1, sel10(dv, l - 1) - p);
        put10(ev, l - 1, gg);
      }
    } else {
      // ---------------- QR iteration ----------------
      for (;;) {
        if (guard++ > 4000) break;
        int m2 = lend;
        if (l != lend) {
          bool fnd = false;
#pragma unroll
          for (int k = n; k >= 2; k--) {
            if (!fnd && k <= l && k >= lend + 1) {
              float e = ev[k - 2];
              if (e * e <= (eps2 * fabsf(dv[k - 1])) * fabsf(dv[k - 2]) + safmin) {
                m2 = k; fnd = true;
              }
            }
          }
        }
        if (m2 > lend) put10(ev, m2 - 2, 0.0f);  // E_(m2-1) = 0
        float p = sel10(dv, l - 1);
        if (m2 == l) {  // eigenvalue found
          put10(dv, l - 1, p);
          l = l - 1;
          if (l >= lend) continue;
          break;
        }
        if (m2 == l - 1) {  // 2x2 block; 0-based cols (l-1, l-2)
          float rt1, rt2, c2, s2;
          slaev2(sel10(dv, l - 2), sel10(ev, l - 2), sel10(dv, l - 1), &rt1, &rt2, &c2, &s2);
          float a = sel10(z, l - 1);
          float b = sel10(z, l - 2);
          put10(z, l - 1, c2 * a - s2 * b);
          put10(z, l - 2, s2 * a + c2 * b);
          put10(dv, l - 2, rt1);
          put10(dv, l - 1, rt2);
          put10(ev, l - 2, 0.0f);
          l = l - 2;
          if (l >= lend) continue;
          break;
        }
        if (jtot == nmaxit) break;
        jtot++;
        float El1 = sel10(ev, l - 2);  // E_(l-1)
        float gg = (sel10(dv, l - 2) - p) / (2.0f * El1);
        float rr = slapy2(gg, 1.0f);
        gg = sel10(dv, m2 - 1) - p + (El1 / (gg + sf_sign(rr, gg)));
        float s = 1.0f, c = 1.0f;
        p = 0.0f;
        // rotation recurrence, static ascending unroll w/ scalar guards
#pragma unroll
        for (int i = 1; i <= n - 1; i++) {
          if (i >= m2 && i <= l - 1) {
            float e = ev[i - 1];
            float f = s * e, b = c * e;
            slartg(gg, f, &c, &s, &rr);
            if (i >= 2) {
              if (i != m2) ev[i - 2] = rr;  // E_(i-1), static
            }
            gg = dv[i - 1] - p;  // D_(i)
            rr = (dv[i] - gg) * s + 2.0f * c * b;
            p = s * rr;
            dv[i - 1] = gg + p;
            gg = c * rr - b;
            csv[i - 1] = c;
            snv[i - 1] = s;
          }
        }
        // apply rotations (slasr 'F'): ascending j, 0-based cols (j, j-1)
        {
          float carry = sel10(z, m2 - 1);  // current value of col j-1
#pragma unroll
          for (int j = 1; j <= n - 1; j++) {
            if (j >= m2 && j <= l - 1) {
              float cj = csv[j - 1], sj = snv[j - 1];  // static
              float t = z[j];                          // untouched original
              z[j - 1] = sj * t + cj * carry;          // final col j-1
              carry = cj * t - sj * carry;             // new col j, carried
            }
          }
          put10(z, l - 1, carry);
        }
        put10(dv, l - 1, sel10(dv, l - 1) - p);
        put10(ev, l - 2, gg);  // E_(l-1)
      }
    }
  }

  // -------- selection sort ascending (as in ssteqr), uniform --------
  for (int ii = 2; ii <= n; ii++) {
    int i = ii - 1;
    int k = i;
    float p = sel10(dv, i - 1);
    for (int j = ii; j <= n; j++) {
      float dj = sel10(dv, j - 1);
      if (dj < p) { k = j; p = dj; }
    }
    if (k != i) {
      float di = sel10(dv, i - 1);
      put10(dv, k - 1, di);
      put10(dv, i - 1, p);
      float a = sel10(z, i - 1), b = sel10(z, k - 1);
      put10(z, i - 1, b);
      put10(z, k - 1, a);
    }
  }

  // -------- MLP per lane (lane r computes output row r) --------
  if (lane < 10) {
    double o = (double)b2[0];
#pragma unroll
    for (int h = 0; h < 16; h++) {
      double sgm = (double)b1[h];
#pragma unroll
      for (int k = 0; k < 10; k++) sgm += (double)z[k] * (double)W1[h * 10 + k];
      if (sgm > 0.0) o += sgm * (double)W2[h];
    }
    double sig = 1.0 / (1.0 + exp(-o));
    out[lane] = (float)(0.5 * (sig + 1.0));
  }
}

extern "C" void kernel_launch(void* const* d_in, const int* in_sizes, int n_in,
                              void* d_out, int out_size, void* d_ws, size_t ws_size,
                              hipStream_t stream) {
  const float* x  = (const float*)d_in[0];
  const float* W1 = (const float*)d_in[1];
  const float* b1 = (const float*)d_in[2];
  const float* W2 = (const float*)d_in[3];
  const float* b2 = (const float*)d_in[4];
  double* g = (double*)d_ws;
  float* out = (float*)d_out;

  int nf4 = in_sizes[0] / 4;  // 10M float4

  zero_ws_kernel<<<1, 256, 0, stream>>>(g);
  gram_kernel<<<GRID2, BLK2, 0, stream>>>((const float4*)x, g, nf4);
  eig_mlp_kernel<<<1, 64, 0, stream>>>(g, W1, b1, W2, b2, out);
}